// Round 5
// baseline (211.624 us; speedup 1.0000x reference)
//
#include <hip/hip_runtime.h>

namespace {
constexpr int IW = 512;
constexpr int IH = 512;
constexpr int ID = 64;
constexpr int PS = IH * IW;                      // plane stride (floats)
constexpr float W_Z  = 0.5f;                     // CONTIZ^2
constexpr float W_XY = 2.0f;
constexpr float W_XZ = 1.41421356237309515f;     // 2*CONTIZ = sqrt(2)

constexpr int TPB  = 256;
constexpr int NSEG = 4;                          // z segments
constexpr int DSEG = ID / NSEG;                  // 16 d-steps per segment
constexpr int RPB  = 8;                          // anchor rows per block
constexpr int SLAB = RPB + 2;                    // 10 staged rows per z-step
constexpr int NF4  = SLAB * (IW / 4);            // 1280 float4 per slab
constexpr int LDK  = NF4 / TPB;                  // 5 float4 per thread
constexpr int BLOCKS = 2 * NSEG * (IH / RPB);    // 512 -> 2 blocks/CU
}

__device__ __forceinline__ void ld8(const float* p, float v[8]) {
    float4 r0 = *(const float4*)p;
    float4 r1 = *(const float4*)(p + 4);
    v[0] = r0.x; v[1] = r0.y; v[2] = r0.z; v[3] = r0.w;
    v[4] = r1.x; v[5] = r1.y; v[6] = r1.z; v[7] = r1.w;
}
__device__ __forceinline__ void zero8(float v[8]) {
    #pragma unroll
    for (int i = 0; i < 8; ++i) v[i] = 0.f;
}
// x first-differences of an 8-float lane chunk (+2 tail elems via shuffle)
__device__ __forceinline__ void dx9(const float v[8], float t8, float t9, float o[9]) {
    #pragma unroll
    for (int i = 0; i < 7; ++i) o[i] = v[i + 1] - v[i];
    o[7] = t8 - v[7];
    o[8] = t9 - t8;
}

// 4 waves/block, 2 blocks/CU; VGPR budget 256
__global__ __launch_bounds__(TPB, 2) void HessianReg_kernel(const float* __restrict__ img,
                                                            float* __restrict__ out) {
    // Double-buffered staged slab: rows stored parity-split
    // [even float4s | odd float4s] so wave reads are 16B-stride ds_read_b128
    // (conflict-free).  2 x 1280 x 16B = 40 KB.
    __shared__ float4 slab[2][NF4];

    // XCD k owns band k = (n,seg): 64 consecutive logical blocks.
    const int lblk = (blockIdx.x & 7) * (BLOCKS / 8) + (blockIdx.x >> 3);
    const int tid  = threadIdx.x;
    const int lane = tid & 63;
    const int wv   = tid >> 6;
    const int q    = lblk >> 6;                        // band id [0,8) == XCD
    const int yg   = lblk & 63;                        // y-group
    const int n    = q & 1;
    const int seg  = q >> 1;
    const int h0   = yg * RPB;                         // block anchor base row
    const int d0   = __builtin_amdgcn_readfirstlane(seg * DSEG);
    const int ha   = h0 + 2 * wv;                      // this wave's anchor row
    const int w0   = lane << 3;

    const float mh = (lane < 63) ? 1.f : 0.f;  // x-tail mask (row end)
    const bool ry2 = (ha < IH - 2);            // wave-uniform y guards
    const bool ry3 = (ha < IH - 3);

    // ---- staging map (fixed per thread): 5 float4, stride-256 distribution
    // g = k*256+tid -> slab row r = g>>7 in [0,10), col c = g&127.
    // coalesced global (consecutive tid -> consecutive 16B) and 16B-swizzled LDS.
    int ridx[LDK], sidx[LDK]; bool rok[LDK];
    #pragma unroll
    for (int k = 0; k < LDK; ++k) {
        const int g = k * TPB + tid;
        const int r = g >> 7, c = g & 127;
        ridx[k] = r * 128 + c;                         // global float4 offset
        sidx[k] = r * 128 + (c & 1) * 64 + (c >> 1);   // parity-swizzled LDS
        rok[k]  = (h0 + r < IH);                       // rows 512/513 -> zero
    }

    // global float4 pointer to slab origin (row h0, col 0) of plane d0+2
    const float4* gplane = (const float4*)img
                         + ((size_t)(n * ID + d0 + 2) * IH + h0) * (IW / 4);
    const float4 Z4 = make_float4(0.f, 0.f, 0.f, 0.f);

    // ---- issue prologue stage: plane d0+2 ----
    float4 stg[LDK];
    #pragma unroll
    for (int k = 0; k < LDK; ++k) stg[k] = rok[k] ? gplane[ridx[k]] : Z4;
    gplane += PS / 4;

    // ---- per-wave prologue: planes d0, d0+1, rows ha..ha+3 (direct loads) ----
    const float* p = img + ((size_t)(n * ID + d0) * IH + ha) * IW + w0;
    float Vc[4][8], Vp[4][8];
    ld8(p, Vc[0]); ld8(p + IW, Vc[1]);
    if (ry2) ld8(p + 2 * IW, Vc[2]); else zero8(Vc[2]);
    if (ry3) ld8(p + 3 * IW, Vc[3]); else zero8(Vc[3]);
    ld8(p + PS, Vp[0]); ld8(p + PS + IW, Vp[1]);       // d0+1 <= 49: valid
    if (ry2) ld8(p + PS + 2 * IW, Vp[2]); else zero8(Vp[2]);
    if (ry3) ld8(p + PS + 3 * IW, Vp[3]); else zero8(Vp[3]);

    // rolled state in first-difference form (same as R4)
    float DXc[3][9], DXn[3][9], DYc[3][8], DYn[3][8], DZc[2][8];
    float Vn0[8], Vn1[8];
    #pragma unroll
    for (int j = 0; j < 3; ++j) {
        float c8 = __shfl_down(Vc[j][0], 1, 64);
        float c9 = __shfl_down(Vc[j][1], 1, 64);
        dx9(Vc[j], c8, c9, DXc[j]);
        float p8 = __shfl_down(Vp[j][0], 1, 64);
        float p9 = __shfl_down(Vp[j][1], 1, 64);
        dx9(Vp[j], p8, p9, DXn[j]);
        #pragma unroll
        for (int i = 0; i < 8; ++i) {
            DYc[j][i] = Vc[j + 1][i] - Vc[j][i];
            DYn[j][i] = Vp[j + 1][i] - Vp[j][i];
        }
    }
    #pragma unroll
    for (int i = 0; i < 8; ++i) {
        DZc[0][i] = Vp[0][i] - Vc[0][i];
        DZc[1][i] = Vp[1][i] - Vc[1][i];
        Vn0[i] = Vp[0][i]; Vn1[i] = Vp[1][i];
    }

    // ---- commit prologue slab ----
    #pragma unroll
    for (int k = 0; k < LDK; ++k) slab[0][sidx[k]] = stg[k];
    __syncthreads();

    float sxx = 0.f, syy = 0.f, szz = 0.f, sxy = 0.f, sxz = 0.f, syz = 0.f;
    int cur = 0;

    #pragma unroll 2
    for (int dl = 0; dl < DSEG; ++dl) {
        const int d = d0 + dl;
        const bool gz1 = (d < ID - 1);   // g_xz/g_yz valid
        const bool gz2 = (d < ID - 2);   // g_zz valid (plane d+2 exists)

        // ---- issue next-plane staging loads (plane d+3) FIRST ----
        const bool pok = (d + 3 < ID);
        #pragma unroll
        for (int k = 0; k < LDK; ++k)
            stg[k] = (pok && rok[k]) ? gplane[ridx[k]] : Z4;
        gplane += PS / 4;

        // ---- read this wave's 4 slab rows of plane d+2 from LDS ----
        float Vf[4][8];
        #pragma unroll
        for (int j = 0; j < 4; ++j) {
            const int rb = (2 * wv + j) * 128;
            float4 u0 = slab[cur][rb + lane];          // even float4 (8l..8l+3)
            float4 u1 = slab[cur][rb + 64 + lane];     // odd  float4 (8l+4..8l+7)
            Vf[j][0] = u0.x; Vf[j][1] = u0.y; Vf[j][2] = u0.z; Vf[j][3] = u0.w;
            Vf[j][4] = u1.x; Vf[j][5] = u1.y; Vf[j][6] = u1.z; Vf[j][7] = u1.w;
        }
        float f8[3], f9[3];
        #pragma unroll
        for (int j = 0; j < 3; ++j) {
            f8[j] = __shfl_down(Vf[j][0], 1, 64);
            f9[j] = __shfl_down(Vf[j][1], 1, 64);
        }

        // ---- accumulate anchors (d, ha) and (d, ha+1) from rolled state ----
        #pragma unroll
        for (int j = 0; j < 2; ++j) {        // g_xx
            #pragma unroll
            for (int i = 0; i < 6; ++i) sxx += fabsf(DXc[j][i + 1] - DXc[j][i]);
            sxx = fmaf(mh, fabsf(DXc[j][7] - DXc[j][6]), sxx);
            sxx = fmaf(mh, fabsf(DXc[j][8] - DXc[j][7]), sxx);
        }
        {                                     // g_xy
            #pragma unroll
            for (int i = 0; i < 7; ++i) sxy += fabsf(DXc[1][i] - DXc[0][i]);
            sxy = fmaf(mh, fabsf(DXc[1][7] - DXc[0][7]), sxy);
            if (ry2) {
                #pragma unroll
                for (int i = 0; i < 7; ++i) sxy += fabsf(DXc[2][i] - DXc[1][i]);
                sxy = fmaf(mh, fabsf(DXc[2][7] - DXc[1][7]), sxy);
            }
        }
        if (gz1) {                            // g_xz
            #pragma unroll
            for (int j = 0; j < 2; ++j) {
                #pragma unroll
                for (int i = 0; i < 7; ++i) sxz += fabsf(DXn[j][i] - DXc[j][i]);
                sxz = fmaf(mh, fabsf(DXn[j][7] - DXc[j][7]), sxz);
            }
        }
        if (ry2) {                            // g_yy
            #pragma unroll
            for (int i = 0; i < 8; ++i) syy += fabsf(DYc[1][i] - DYc[0][i]);
        }
        if (ry3) {
            #pragma unroll
            for (int i = 0; i < 8; ++i) syy += fabsf(DYc[2][i] - DYc[1][i]);
        }
        if (gz1) {                            // g_yz
            #pragma unroll
            for (int i = 0; i < 8; ++i) syz += fabsf(DYn[0][i] - DYc[0][i]);
            if (ry2) {
                #pragma unroll
                for (int i = 0; i < 8; ++i) syz += fabsf(DYn[1][i] - DYc[1][i]);
            }
        }
        {                                     // g_zz + DZ roll
            float dzf0[8], dzf1[8];
            #pragma unroll
            for (int i = 0; i < 8; ++i) {
                dzf0[i] = Vf[0][i] - Vn0[i];
                dzf1[i] = Vf[1][i] - Vn1[i];
            }
            if (gz2) {
                #pragma unroll
                for (int i = 0; i < 8; ++i) szz += fabsf(dzf0[i] - DZc[0][i]);
                #pragma unroll
                for (int i = 0; i < 8; ++i) szz += fabsf(dzf1[i] - DZc[1][i]);
            }
            #pragma unroll
            for (int i = 0; i < 8; ++i) { DZc[0][i] = dzf0[i]; DZc[1][i] = dzf1[i]; }
        }

        // ---- roll planes ----
        #pragma unroll
        for (int j = 0; j < 3; ++j) {
            #pragma unroll
            for (int i = 0; i < 9; ++i) DXc[j][i] = DXn[j][i];
            #pragma unroll
            for (int i = 0; i < 8; ++i) DYc[j][i] = DYn[j][i];
        }
        #pragma unroll
        for (int j = 0; j < 3; ++j) {
            dx9(Vf[j], f8[j], f9[j], DXn[j]);
            #pragma unroll
            for (int i = 0; i < 8; ++i) DYn[j][i] = Vf[j + 1][i] - Vf[j][i];
        }
        #pragma unroll
        for (int i = 0; i < 8; ++i) { Vn0[i] = Vf[0][i]; Vn1[i] = Vf[1][i]; }

        // ---- commit next slab (waits vmcnt on stg), one barrier per step ----
        #pragma unroll
        for (int k = 0; k < LDK; ++k) slab[cur ^ 1][sidx[k]] = stg[k];
        __syncthreads();
        cur ^= 1;
    }

    float acc = sxx + syy + W_Z * szz + W_XY * sxy + W_XZ * (sxz + syz);

    // wave (64-lane) shuffle reduce
    for (int off = 32; off > 0; off >>= 1)
        acc += __shfl_down(acc, off, 64);

    __shared__ float ws[TPB / 64];
    if (lane == 0) ws[wv] = acc;
    __syncthreads();
    if (tid == 0) {
        float bsum = 0.f;
        #pragma unroll
        for (int i = 0; i < TPB / 64; ++i) bsum += ws[i];
        atomicAdd(out, bsum * (1.0f / (IH * IW)));
    }
}

extern "C" void kernel_launch(void* const* d_in, const int* in_sizes, int n_in,
                              void* d_out, int out_size, void* d_ws, size_t ws_size,
                              hipStream_t stream) {
    const float* img = (const float*)d_in[0];
    float* out = (float*)d_out;
    // d_out is re-poisoned to 0xAA before every timed launch -> zero it on-stream.
    hipMemsetAsync(out, 0, sizeof(float), stream);
    hipLaunchKernelGGL(HessianReg_kernel, dim3(BLOCKS), dim3(TPB), 0, stream, img, out);
}

// Round 6
// 192.336 us; speedup vs baseline: 1.1003x; 1.1003x over previous
//
#include <hip/hip_runtime.h>

namespace {
constexpr int IW = 512;
constexpr int IH = 512;
constexpr int ID = 64;
constexpr int PS = IH * IW;                      // plane stride (floats)
constexpr float W_Z  = 0.5f;                     // CONTIZ^2
constexpr float W_XY = 2.0f;
constexpr float W_XZ = 1.41421356237309515f;     // 2*CONTIZ = sqrt(2)

constexpr int TPB    = 256;
constexpr int NSEG   = 4;                        // z segments
constexpr int DSEG   = ID / NSEG;                // 16 d-steps per segment
// one wave = one anchor-row PAIR: 2(n) x 4(seg) x 256(pairs) = 2048 waves
constexpr int BLOCKS = 2 * NSEG * (IH / 2) / (TPB / 64);   // 512
}

__device__ __forceinline__ void ld8(const float* p, float v[8]) {
    float4 r0 = *(const float4*)p;
    float4 r1 = *(const float4*)(p + 4);
    v[0] = r0.x; v[1] = r0.y; v[2] = r0.z; v[3] = r0.w;
    v[4] = r1.x; v[5] = r1.y; v[6] = r1.z; v[7] = r1.w;
}
__device__ __forceinline__ void zero8(float v[8]) {
    #pragma unroll
    for (int i = 0; i < 8; ++i) v[i] = 0.f;
}
// x first-differences of an 8-float lane chunk (+2 tail elems via shuffle)
__device__ __forceinline__ void dx9(const float v[8], float t8, float t9, float o[9]) {
    #pragma unroll
    for (int i = 0; i < 7; ++i) o[i] = v[i + 1] - v[i];
    o[7] = t8 - v[7];
    o[8] = t9 - t8;
}

// 4 waves/block; 2 blocks/CU (grid-limited) -> VGPR budget 256
__global__ __launch_bounds__(TPB, 2) void HessianReg_kernel(const float* __restrict__ img,
                                                            float* __restrict__ out) {
    // XCD k owns band k = (n,seg) entirely: 64 consecutive logical blocks.
    const int lblk = (blockIdx.x & 7) * (BLOCKS / 8) + (blockIdx.x >> 3);
    const int tid  = threadIdx.x;
    const int lane = tid & 63;
    const int P    = lblk * (TPB / 64) + (tid >> 6);   // pair task [0,2048)
    const int h2   = P & 255;
    const int q    = P >> 8;                           // band id [0,8) == XCD
    const int n    = q & 1;
    const int seg  = q >> 1;
    const int h    = h2 << 1;                          // even anchor row
    const int d0   = __builtin_amdgcn_readfirstlane(seg * DSEG);
    const int w0   = lane << 3;

    const float mh = (lane < 63) ? 1.f : 0.f;  // x-tail mask (row end)
    const bool ry2 = (h < IH - 2);             // row h+2 exists (false only h=510)
    const bool ry3 = (h < IH - 3);             // row h+3 exists

    const float* p = img + ((size_t)(n * ID + d0) * IH + h) * IW + w0;

    // ---- prologue: slabs of planes d0 and d0+1 (rows h..h+3) ----
    float Vc[4][8], Vp[4][8];
    ld8(p, Vc[0]); ld8(p + IW, Vc[1]);
    if (ry2) ld8(p + 2 * IW, Vc[2]); else zero8(Vc[2]);
    if (ry3) ld8(p + 3 * IW, Vc[3]); else zero8(Vc[3]);
    ld8(p + PS, Vp[0]); ld8(p + PS + IW, Vp[1]);       // d0+1 <= 49: valid
    if (ry2) ld8(p + PS + 2 * IW, Vp[2]); else zero8(Vp[2]);
    if (ry3) ld8(p + PS + 3 * IW, Vp[3]); else zero8(Vp[3]);

    // rolled state (all first-difference form):
    // DXc/DXn: x-diffs rows 0..2 at planes d, d+1
    // DYc/DYn: y-diffs (row j+1 - row j), j=0..2, at planes d, d+1
    // DZc    : z-diff  (plane d+1 - plane d), rows 0..1
    // Vn0/Vn1: plane d+1 values rows 0..1 (for next DZ)
    float DXc[3][9], DXn[3][9], DYc[3][8], DYn[3][8], DZc[2][8];
    float Vn0[8], Vn1[8];
    #pragma unroll
    for (int j = 0; j < 3; ++j) {
        float c8 = __shfl_down(Vc[j][0], 1, 64);
        float c9 = __shfl_down(Vc[j][1], 1, 64);
        dx9(Vc[j], c8, c9, DXc[j]);
        float p8 = __shfl_down(Vp[j][0], 1, 64);
        float p9 = __shfl_down(Vp[j][1], 1, 64);
        dx9(Vp[j], p8, p9, DXn[j]);
        #pragma unroll
        for (int i = 0; i < 8; ++i) {
            DYc[j][i] = Vc[j + 1][i] - Vc[j][i];
            DYn[j][i] = Vp[j + 1][i] - Vp[j][i];
        }
    }
    #pragma unroll
    for (int i = 0; i < 8; ++i) {
        DZc[0][i] = Vp[0][i] - Vc[0][i];
        DZc[1][i] = Vp[1][i] - Vc[1][i];
        Vn0[i] = Vp[0][i]; Vn1[i] = Vp[1][i];
    }

    float sxx = 0.f, syy = 0.f, szz = 0.f, sxy = 0.f, sxz = 0.f, syz = 0.f;

    #pragma unroll 2
    for (int dl = 0; dl < DSEG; ++dl) {
        const int d = d0 + dl;
        const bool gz1 = (d < ID - 1);   // g_xz/g_yz valid (needs plane d+1)
        const bool gz2 = (d < ID - 2);   // g_zz valid == plane d+2 exists

        // ---- load slab of plane d+2: each row exactly once per wave ----
        float Vf[4][8];
        if (gz2) {
            ld8(p + 2 * PS, Vf[0]); ld8(p + 2 * PS + IW, Vf[1]);
            if (ry2) ld8(p + 2 * PS + 2 * IW, Vf[2]); else zero8(Vf[2]);
            if (ry3) ld8(p + 2 * PS + 3 * IW, Vf[3]); else zero8(Vf[3]);
        } else {
            zero8(Vf[0]); zero8(Vf[1]); zero8(Vf[2]); zero8(Vf[3]);
        }
        float f8[3], f9[3];
        #pragma unroll
        for (int j = 0; j < 3; ++j) {
            f8[j] = __shfl_down(Vf[j][0], 1, 64);
            f9[j] = __shfl_down(Vf[j][1], 1, 64);
        }

        // ---- accumulate anchors (d, h) and (d, h+1) from rolled state ----
        // g_xx: second x-diffs, rows j=0,1 (last two terms lane63-masked)
        #pragma unroll
        for (int j = 0; j < 2; ++j) {
            #pragma unroll
            for (int i = 0; i < 6; ++i) sxx += fabsf(DXc[j][i + 1] - DXc[j][i]);
            sxx = fmaf(mh, fabsf(DXc[j][7] - DXc[j][6]), sxx);
            sxx = fmaf(mh, fabsf(DXc[j][8] - DXc[j][7]), sxx);
        }
        // g_xy = |dx(row j+1) - dx(row j)|, anchors j=0 (always), j=1 (ry2)
        {
            #pragma unroll
            for (int i = 0; i < 7; ++i) sxy += fabsf(DXc[1][i] - DXc[0][i]);
            sxy = fmaf(mh, fabsf(DXc[1][7] - DXc[0][7]), sxy);
            if (ry2) {
                #pragma unroll
                for (int i = 0; i < 7; ++i) sxy += fabsf(DXc[2][i] - DXc[1][i]);
                sxy = fmaf(mh, fabsf(DXc[2][7] - DXc[1][7]), sxy);
            }
        }
        // g_xz = |dx(plane d+1) - dx(plane d)|, rows j=0,1
        if (gz1) {
            #pragma unroll
            for (int j = 0; j < 2; ++j) {
                #pragma unroll
                for (int i = 0; i < 7; ++i) sxz += fabsf(DXn[j][i] - DXc[j][i]);
                sxz = fmaf(mh, fabsf(DXn[j][7] - DXc[j][7]), sxz);
            }
        }
        // g_yy = |dy(j+1) - dy(j)|, anchors j=0 (ry2), j=1 (ry3)
        if (ry2) {
            #pragma unroll
            for (int i = 0; i < 8; ++i) syy += fabsf(DYc[1][i] - DYc[0][i]);
        }
        if (ry3) {
            #pragma unroll
            for (int i = 0; i < 8; ++i) syy += fabsf(DYc[2][i] - DYc[1][i]);
        }
        // g_yz = |dy(plane d+1) - dy(plane d)|, anchors j=0 (always), j=1 (ry2)
        if (gz1) {
            #pragma unroll
            for (int i = 0; i < 8; ++i) syz += fabsf(DYn[0][i] - DYc[0][i]);
            if (ry2) {
                #pragma unroll
                for (int i = 0; i < 8; ++i) syz += fabsf(DYn[1][i] - DYc[1][i]);
            }
        }
        // g_zz = |dz(d+1->d+2) - dz(d->d+1)|, rows j=0,1; then roll DZ
        {
            float dzf0[8], dzf1[8];
            #pragma unroll
            for (int i = 0; i < 8; ++i) { dzf0[i] = Vf[0][i] - Vn0[i]; dzf1[i] = Vf[1][i] - Vn1[i]; }
            if (gz2) {
                #pragma unroll
                for (int i = 0; i < 8; ++i) szz += fabsf(dzf0[i] - DZc[0][i]);
                #pragma unroll
                for (int i = 0; i < 8; ++i) szz += fabsf(dzf1[i] - DZc[1][i]);
            }
            #pragma unroll
            for (int i = 0; i < 8; ++i) { DZc[0][i] = dzf0[i]; DZc[1][i] = dzf1[i]; }
        }

        // ---- roll planes (copies renamed away by unroll 2) ----
        #pragma unroll
        for (int j = 0; j < 3; ++j) {
            #pragma unroll
            for (int i = 0; i < 9; ++i) DXc[j][i] = DXn[j][i];
            #pragma unroll
            for (int i = 0; i < 8; ++i) DYc[j][i] = DYn[j][i];
        }
        #pragma unroll
        for (int j = 0; j < 3; ++j) {
            dx9(Vf[j], f8[j], f9[j], DXn[j]);
            #pragma unroll
            for (int i = 0; i < 8; ++i) DYn[j][i] = Vf[j + 1][i] - Vf[j][i];
        }
        #pragma unroll
        for (int i = 0; i < 8; ++i) { Vn0[i] = Vf[0][i]; Vn1[i] = Vf[1][i]; }
        p += PS;
    }

    float acc = sxx + syy + W_Z * szz + W_XY * sxy + W_XZ * (sxz + syz);

    // wave (64-lane) shuffle reduce
    for (int off = 32; off > 0; off >>= 1)
        acc += __shfl_down(acc, off, 64);

    __shared__ float ws[TPB / 64];
    const int wv = tid >> 6;
    if (lane == 0) ws[wv] = acc;
    __syncthreads();
    if (tid == 0) {
        float bsum = 0.f;
        #pragma unroll
        for (int i = 0; i < TPB / 64; ++i) bsum += ws[i];
        atomicAdd(out, bsum * (1.0f / (IH * IW)));
    }
}

extern "C" void kernel_launch(void* const* d_in, const int* in_sizes, int n_in,
                              void* d_out, int out_size, void* d_ws, size_t ws_size,
                              hipStream_t stream) {
    const float* img = (const float*)d_in[0];
    float* out = (float*)d_out;
    // d_out is re-poisoned to 0xAA before every timed launch -> zero it on-stream.
    hipMemsetAsync(out, 0, sizeof(float), stream);
    hipLaunchKernelGGL(HessianReg_kernel, dim3(BLOCKS), dim3(TPB), 0, stream, img, out);
}